// Round 8
// baseline (222.846 us; speedup 1.0000x reference)
//
#include <hip/hip_runtime.h>

// Trilinear 3D-LUT apply: lut [1,3,33,33,33] f32, x [8,3,1024,1024] f32 in [0,1)
// out [8,3,1024,1024] f32.
//
// V7 = V6's enforced prefetch pipeline (sched_barrier(0), proven -10.5us)
//    + V3b's fp16 b-pair LDS cube (4 random LDS addresses/pixel instead of 8;
//      conflicts measured 7.96e6 vs 1.59e7) + v_dot2_f32_f16 b-lerp.
// Diagnosis: V6's LDS pipe is ~70% busy (6144 ds_read2/CU x ~22cy incl. 10cy
// avg conflict replay = ~56us of 79.5) -- the busiest resource. Halving the
// address count halves both issue and replay: LDS ~28us, leaving HBM (~41us
// floor at 251MB) as the binding resource.
// LDS = 143,744 B -> still 1 block/CU, 16 waves (occupancy unchanged; V5
// proved occupancy was not the constraint anyway).

#define D   33
#define D2  (33 * 33)
#define D3  (33 * 33 * 33)       // 35937
#define NP  (D3 - 1)             // fp16-pair entries: 35936 * 4 B = 143,744 B
#define HW  (1024 * 1024)
#define QHW (HW / 4)             // float4 groups per plane = 2^18
#define CHUNKS 256
#define GPC ((8 * QHW) / CHUNKS) // groups per chunk = 8192
#define THREADS 1024
#define ITERS (GPC / THREADS)    // 8 float4-groups per thread

typedef __fp16 h16;
typedef __attribute__((ext_vector_type(2))) __fp16 h16x2;

#define DOT2(a, b) __builtin_amdgcn_fdot2((a), (b), 0.0f, false)

__global__ __launch_bounds__(THREADS) void lut3d_kernel(
    const float* __restrict__ lut, const float* __restrict__ x,
    float* __restrict__ out)
{
    const int c     = blockIdx.x;   // channel fastest: chunk-triple adjacent -> L2 x-sharing
    const int chunk = blockIdx.y;

    // --- stage channel cube as fp16 b-pairs: ls[i] = (lut[i], lut[i+1]) -----
    __shared__ h16x2 ls[NP];
    {
        const float* lc = lut + c * D3;
        for (int i = threadIdx.x; i < NP; i += THREADS) {
            h16x2 v;
            v.x = (h16)lc[i];
            v.y = (h16)lc[i + 1];
            ls[i] = v;
        }
    }
    __syncthreads();

    const int tid  = threadIdx.x;
    const int base = chunk * GPC;            // chunk never straddles a batch plane
    const int bidx = base >> 18;             // batch index, block-constant
    const int pb   = (base & (QHW - 1)) * 4; // float offset of chunk in plane

    const float* xp = x   + (size_t)bidx * 3 * HW + pb;
    float*       op = out + (size_t)bidx * 3 * HW + (size_t)c * HW + pb;

    // load the 3 channel float4s of group `it`
    auto LD = [&](int it, float4& r, float4& g, float4& b) {
        const int fo = it * (THREADS * 4) + tid * 4;
        r = *(const float4*)(xp + fo);
        g = *(const float4*)(xp + fo + HW);
        b = *(const float4*)(xp + fo + 2 * HW);
    };

    // compute + store one float4-group (4 pixels)
    auto DO = [&](int it, const float4& xr, const float4& xg, const float4& xB) {
        const float rr[4] = {xr.x, xr.y, xr.z, xr.w};
        const float gg[4] = {xg.x, xg.y, xg.z, xg.w};
        const float bb[4] = {xB.x, xB.y, xB.z, xB.w};
        float oo[4];
        #pragma unroll
        for (int j = 0; j < 4; ++j) {
            // clamp(x,0,1)*32 capped below 32: i0<=31 always -> +1/+33/+1089
            // neighbor offsets are compile-time constants; the 4 pair-loads
            // (dword offsets {0,33} from bases idx, idx+1089) merge into
            // 2x ds_read2_b32.
            const float vr = fminf(fmaxf(rr[j], 0.f) * 32.f, 31.999998f);
            const float vg = fminf(fmaxf(gg[j], 0.f) * 32.f, 31.999998f);
            const float vb = fminf(fmaxf(bb[j], 0.f) * 32.f, 31.999998f);

            const int r0 = (int)vr, g0 = (int)vg, b0 = (int)vb;  // trunc==floor
            const float fr = vr - (float)r0;
            const float fg = vg - (float)g0;
            const float fb = vb - (float)b0;

            const int idx = __mul24(r0, D2) + __mul24(g0, D) + b0;

            const h16x2 h00 = ls[idx];            // (c000, c001)
            const h16x2 h01 = ls[idx + D];        // (c010, c011)
            const h16x2 h10 = ls[idx + D2];       // (c100, c101)
            const h16x2 h11 = ls[idx + D2 + D];   // (c110, c111)

            // b-lerp: one v_dot2_f32_f16 per corner pair, f32 accumulate
            const h16x2 w = __builtin_amdgcn_cvt_pkrtz(1.0f - fb, fb);
            const float c00 = DOT2(h00, w);
            const float c01 = DOT2(h01, w);
            const float c10 = DOT2(h10, w);
            const float c11 = DOT2(h11, w);

            const float cg0 = c00 + fg * (c01 - c00);
            const float cg1 = c10 + fg * (c11 - c10);
            oo[j] = cg0 + fr * (cg1 - cg0);
        }
        const int fo = it * (THREADS * 4) + tid * 4;
        *(float4*)(op + fo) = make_float4(oo[0], oo[1], oo[2], oo[3]);
    };

    // --- enforced 2-deep software pipeline (V6-proven) ----------------------
    float4 ar, ag, ab_, br, bg, bb_;
    LD(0, ar, ag, ab_);
    LD(1, br, bg, bb_);

    #pragma unroll 1
    for (int it = 0; it < ITERS - 2; it += 2) {
        float4 nr, ng, nb_, mr, mg, mb_;
        LD(it + 2, nr, ng, nb_);             // issue next pair's 6 loads FIRST
        LD(it + 3, mr, mg, mb_);
        __builtin_amdgcn_sched_barrier(0);   // loads may not sink below
        DO(it,     ar, ag, ab_);
        DO(it + 1, br, bg, bb_);
        ar = nr; ag = ng; ab_ = nb_;
        br = mr; bg = mg; bb_ = mb_;
    }
    DO(ITERS - 2, ar, ag, ab_);              // drain
    DO(ITERS - 1, br, bg, bb_);
}

extern "C" void kernel_launch(void* const* d_in, const int* in_sizes, int n_in,
                              void* d_out, int out_size, void* d_ws, size_t ws_size,
                              hipStream_t stream) {
    const float* lut = (const float*)d_in[0];   // [1,3,33,33,33]
    const float* x   = (const float*)d_in[1];   // [8,3,1024,1024]
    float* out = (float*)d_out;                 // [8,3,1024,1024]

    dim3 grid(3, CHUNKS);
    lut3d_kernel<<<grid, THREADS, 0, stream>>>(lut, x, out);
}

// Round 9
// 209.406 us; speedup vs baseline: 1.0642x; 1.0642x over previous
//
#include <hip/hip_runtime.h>

// Trilinear 3D-LUT apply: lut [1,3,33,33,33] f32, x [8,3,1024,1024] f32 in [0,1)
// out [8,3,1024,1024] f32.
//
// V8 = V6 (f32 cube, 8 f32 gathers -> 4x ds_read2_b32, clamp-trick const
//      offsets, enforced prefetch) with the prefetch taken to FULL DEPTH:
//      all 8 groups' x loads (24 float4, ~96 VGPR) issued at loop start,
//      fenced by sched_barrier(0); compute consumes them in order via the
//      compiler's minimal vmcnt waits. Global-load latency is paid once per
//      block, not once per 2-group step.
// Rationale: V7 falsified the LDS-throughput theory (half the conflicts,
//      +22us). The binding constraint is exposed latency; V6's depth-2
//      pipeline was the only causal win (-10.5us, HBM 2.87->3.23). This is
//      that lever at maximum.
// Occupancy note: LDS 143,748 B pins 1 block/CU (16 waves) regardless of
//      VGPR, so ~150 VGPR is free (<= 512/wave available at 4 waves/SIMD).
// Success criterion: VGPR_Count ~120-170. Predicted dispatch 79.5 -> 58-68us.

#define D   33
#define D2  (33 * 33)
#define D3  (33 * 33 * 33)       // 35937 floats = 143,748 B LDS
#define HW  (1024 * 1024)
#define QHW (HW / 4)             // float4 groups per plane = 2^18
#define CHUNKS 256
#define GPC ((8 * QHW) / CHUNKS) // groups per chunk = 8192
#define THREADS 1024
#define ITERS (GPC / THREADS)    // 8 float4-groups per thread

__global__ __launch_bounds__(THREADS) void lut3d_kernel(
    const float* __restrict__ lut, const float* __restrict__ x,
    float* __restrict__ out)
{
    const int c     = blockIdx.x;   // channel fastest: chunk-triple adjacent -> L2 x-sharing
    const int chunk = blockIdx.y;

    // --- stage one channel cube in f32 --------------------------------------
    __shared__ float ls[D3];
    {
        const float* lc = lut + c * D3;
        for (int i = threadIdx.x; i < D3; i += THREADS) ls[i] = lc[i];
    }
    __syncthreads();

    const int tid  = threadIdx.x;
    const int base = chunk * GPC;            // chunk never straddles a batch plane
    const int bidx = base >> 18;             // batch index, block-constant
    const int pb   = (base & (QHW - 1)) * 4; // float offset of chunk in plane

    const float* xp = x   + (size_t)bidx * 3 * HW + pb;
    float*       op = out + (size_t)bidx * 3 * HW + (size_t)c * HW + pb;

    // --- issue ALL x loads up front (24 float4 in flight per lane) ----------
    // Arrays are indexed only by fully-unrolled induction vars -> all indices
    // compile-time constants -> registers, not scratch (rule #20).
    float4 xr[ITERS], xg[ITERS], xB[ITERS];
    #pragma unroll
    for (int it = 0; it < ITERS; ++it) {
        const int fo = it * (THREADS * 4) + tid * 4;
        xr[it] = *(const float4*)(xp + fo);
        xg[it] = *(const float4*)(xp + fo + HW);
        xB[it] = *(const float4*)(xp + fo + 2 * HW);
    }
    __builtin_amdgcn_sched_barrier(0);       // loads may not sink below

    // --- compute all groups; vmcnt waits drain loads in order ---------------
    #pragma unroll
    for (int it = 0; it < ITERS; ++it) {
        const float rr[4] = {xr[it].x, xr[it].y, xr[it].z, xr[it].w};
        const float gg[4] = {xg[it].x, xg[it].y, xg[it].z, xg[it].w};
        const float bb[4] = {xB[it].x, xB[it].y, xB[it].z, xB[it].w};
        float oo[4];

        #pragma unroll
        for (int j = 0; j < 4; ++j) {
            // clamp(x,0,1)*32 capped below 32: i0<=31 always -> +1/+33/+1089
            // neighbor offsets are compile-time constants; gather pairs merge
            // into ds_read2_b32.
            const float vr = fminf(fmaxf(rr[j], 0.f) * 32.f, 31.999998f);
            const float vg = fminf(fmaxf(gg[j], 0.f) * 32.f, 31.999998f);
            const float vb = fminf(fmaxf(bb[j], 0.f) * 32.f, 31.999998f);

            const int r0 = (int)vr, g0 = (int)vg, b0 = (int)vb;  // trunc==floor
            const float fr = vr - (float)r0;
            const float fg = vg - (float)g0;
            const float fb = vb - (float)b0;

            const int idx = __mul24(r0, D2) + __mul24(g0, D) + b0;

            const float c000 = ls[idx];
            const float c001 = ls[idx + 1];
            const float c010 = ls[idx + D];
            const float c011 = ls[idx + D + 1];
            const float c100 = ls[idx + D2];
            const float c101 = ls[idx + D2 + 1];
            const float c110 = ls[idx + D2 + D];
            const float c111 = ls[idx + D2 + D + 1];

            const float c00 = c000 + fb * (c001 - c000);
            const float c01 = c010 + fb * (c011 - c010);
            const float c10 = c100 + fb * (c101 - c100);
            const float c11 = c110 + fb * (c111 - c110);
            const float c0  = c00 + fg * (c01 - c00);
            const float c1  = c10 + fg * (c11 - c10);
            oo[j] = c0 + fr * (c1 - c0);
        }

        const int fo = it * (THREADS * 4) + tid * 4;
        *(float4*)(op + fo) = make_float4(oo[0], oo[1], oo[2], oo[3]);
    }
}

extern "C" void kernel_launch(void* const* d_in, const int* in_sizes, int n_in,
                              void* d_out, int out_size, void* d_ws, size_t ws_size,
                              hipStream_t stream) {
    const float* lut = (const float*)d_in[0];   // [1,3,33,33,33]
    const float* x   = (const float*)d_in[1];   // [8,3,1024,1024]
    float* out = (float*)d_out;                 // [8,3,1024,1024]

    dim3 grid(3, CHUNKS);
    lut3d_kernel<<<grid, THREADS, 0, stream>>>(lut, x, out);
}

// Round 10
// 201.445 us; speedup vs baseline: 1.1062x; 1.0395x over previous
//
#include <hip/hip_runtime.h>

// Trilinear 3D-LUT apply: lut [1,3,33,33,33] f32, x [8,3,1024,1024] f32 in [0,1)
// out [8,3,1024,1024] f32.
//
// V9 = V6 (f32 cube, clamp-trick const-offset gathers, enforced prefetch)
//      with the register budget UNBLOCKED: __launch_bounds__(1024, 4).
// Diagnosis: V8's spill traffic (WRITE 98->110 MB, VGPR capped at 64) exposed
// that the RA budgets for 8 waves/EU by default; LDS (143.7 KB) already pins
// 1 block/CU = 4 waves/EU, so capping VGPR at 64 buys nothing and killed every
// pipelining attempt (V4 sank loads at 52; V8 spilled at 64). Declaring
// (1024, 4) raises the cap to 128 VGPR at zero occupancy cost.
// Pipeline: prefetch distance 3 groups, fully unrolled (static indexing ->
// registers), sched_barrier(0) between LD and DO so loads cannot sink.
// Live x data: 4 groups x 3 float4 = 48 VGPR; total ~95-115 < 128.
//
// Success criteria: VGPR ~90-128, WRITE back to 98304 KB (no scratch),
// hbm 3.2 -> 4-4.8 TB/s, dispatch 79.5 -> 58-68 us.

#define D   33
#define D2  (33 * 33)
#define D3  (33 * 33 * 33)       // 35937 floats = 143,748 B LDS -> 1 block/CU
#define HW  (1024 * 1024)
#define QHW (HW / 4)             // float4 groups per plane = 2^18
#define CHUNKS 256
#define GPC ((8 * QHW) / CHUNKS) // groups per chunk = 8192
#define THREADS 1024
#define ITERS (GPC / THREADS)    // 8 float4-groups per thread
#define PFD 3                    // prefetch distance (groups)

__global__ __launch_bounds__(THREADS, 4) void lut3d_kernel(
    const float* __restrict__ lut, const float* __restrict__ x,
    float* __restrict__ out)
{
    const int c     = blockIdx.x;   // channel fastest: chunk-triple adjacent -> L2 x-sharing
    const int chunk = blockIdx.y;

    // --- stage one channel cube in f32 --------------------------------------
    __shared__ float ls[D3];
    {
        const float* lc = lut + c * D3;
        for (int i = threadIdx.x; i < D3; i += THREADS) ls[i] = lc[i];
    }
    __syncthreads();

    const int tid  = threadIdx.x;
    const int base = chunk * GPC;            // chunk never straddles a batch plane
    const int bidx = base >> 18;             // batch index, block-constant
    const int pb   = (base & (QHW - 1)) * 4; // float offset of chunk in plane

    const float* xp = x   + (size_t)bidx * 3 * HW + pb;
    float*       op = out + (size_t)bidx * 3 * HW + (size_t)c * HW + pb;

    // x data for all groups; ONLY statically-indexed (loops fully unrolled)
    // so elements live in registers with per-element liveness (rule #20).
    float4 xr[ITERS], xg[ITERS], xB[ITERS];

    auto LD = [&](int it) {
        const int fo = it * (THREADS * 4) + tid * 4;
        xr[it] = *(const float4*)(xp + fo);
        xg[it] = *(const float4*)(xp + fo + HW);
        xB[it] = *(const float4*)(xp + fo + 2 * HW);
    };

    auto DO = [&](int it) {
        const float rr[4] = {xr[it].x, xr[it].y, xr[it].z, xr[it].w};
        const float gg[4] = {xg[it].x, xg[it].y, xg[it].z, xg[it].w};
        const float bb[4] = {xB[it].x, xB[it].y, xB[it].z, xB[it].w};
        float oo[4];
        #pragma unroll
        for (int j = 0; j < 4; ++j) {
            // clamp(x,0,1)*32 capped below 32: i0<=31 always -> +1/+33/+1089
            // neighbor offsets are compile-time constants; gather pairs merge
            // into ds_read2_b32.
            const float vr = fminf(fmaxf(rr[j], 0.f) * 32.f, 31.999998f);
            const float vg = fminf(fmaxf(gg[j], 0.f) * 32.f, 31.999998f);
            const float vb = fminf(fmaxf(bb[j], 0.f) * 32.f, 31.999998f);

            const int r0 = (int)vr, g0 = (int)vg, b0 = (int)vb;  // trunc==floor
            const float fr = vr - (float)r0;
            const float fg = vg - (float)g0;
            const float fb = vb - (float)b0;

            const int idx = __mul24(r0, D2) + __mul24(g0, D) + b0;

            const float c000 = ls[idx];
            const float c001 = ls[idx + 1];
            const float c010 = ls[idx + D];
            const float c011 = ls[idx + D + 1];
            const float c100 = ls[idx + D2];
            const float c101 = ls[idx + D2 + 1];
            const float c110 = ls[idx + D2 + D];
            const float c111 = ls[idx + D2 + D + 1];

            const float c00 = c000 + fb * (c001 - c000);
            const float c01 = c010 + fb * (c011 - c010);
            const float c10 = c100 + fb * (c101 - c100);
            const float c11 = c110 + fb * (c111 - c110);
            const float c0  = c00 + fg * (c01 - c00);
            const float c1  = c10 + fg * (c11 - c10);
            oo[j] = c0 + fr * (c1 - c0);
        }
        const int fo = it * (THREADS * 4) + tid * 4;
        *(float4*)(op + fo) = make_float4(oo[0], oo[1], oo[2], oo[3]);
    };

    // --- prologue: fill the pipe (PFD groups = 9 loads in flight) -----------
    #pragma unroll
    for (int it = 0; it < PFD; ++it) LD(it);

    // --- steady state: issue group it+PFD, then compute group it ------------
    #pragma unroll
    for (int it = 0; it < ITERS; ++it) {
        if (it + PFD < ITERS) LD(it + PFD);   // compile-time branch after unroll
        __builtin_amdgcn_sched_barrier(0);    // loads may not sink below
        DO(it);
    }
}

extern "C" void kernel_launch(void* const* d_in, const int* in_sizes, int n_in,
                              void* d_out, int out_size, void* d_ws, size_t ws_size,
                              hipStream_t stream) {
    const float* lut = (const float*)d_in[0];   // [1,3,33,33,33]
    const float* x   = (const float*)d_in[1];   // [8,3,1024,1024]
    float* out = (float*)d_out;                 // [8,3,1024,1024]

    dim3 grid(3, CHUNKS);
    lut3d_kernel<<<grid, THREADS, 0, stream>>>(lut, x, out);
}